// Round 1
// baseline (88.327 us; speedup 1.0000x reference)
//
#include <hip/hip_runtime.h>
#include <math.h>

#define HDIM  512
#define NH    32
#define LLEN  8192
#define BLOCK 256
#define CHUNK (LLEN / BLOCK)   // 32 l-values per thread, strided by BLOCK

// One block per h. Thread tid owns l = tid + BLOCK*j, j in [0, CHUNK).
// T_{n,j} = exp(dtA_n * (tid + BLOCK*j)) advanced by the fixed complex
// multiplier w = exp(dtA_n * BLOCK). Base angle reduced mod 2pi in fp64.
__global__ __launch_bounds__(BLOCK) void s4d_kernel(
    const float* __restrict__ C,          // (H, NH, 2)
    const float* __restrict__ log_dt,     // (H,)
    const float* __restrict__ log_A_real, // (H, NH)
    const float* __restrict__ A_imag,     // (H, NH)
    float* __restrict__ out)              // (H, LLEN)
{
    __shared__ float  s_cre[NH], s_cim[NH];   // 2 * C_scaled
    __shared__ float  s_wre[NH], s_wim[NH];   // exp(dtA * BLOCK)
    __shared__ float  s_dre[NH];              // Re(dtA)
    __shared__ double s_dim[NH];              // Im(dtA) in fp64 for reduction

    const int h   = blockIdx.x;
    const int tid = threadIdx.x;

    if (tid < NH) {
        const int n = tid;
        const double TWO_PI = 6.283185307179586476925287;
        const double dt  = exp((double)log_dt[h]);
        const double Are = -exp((double)log_A_real[h * NH + n]);
        const double Aim = (double)A_imag[h * NH + n];
        const double dre = Are * dt, dim = Aim * dt;

        // C_scaled = Cc * (exp(dtA) - 1) / A   (all fp64)
        double es, ec;
        sincos(dim, &es, &ec);
        const double em   = exp(dre);
        const double nre  = em * ec - 1.0, nim = em * es;
        const double den  = Are * Are + Aim * Aim;
        const double fre  = (nre * Are + nim * Aim) / den;
        const double fim  = (nim * Are - nre * Aim) / den;
        const double Cre  = (double)C[(h * NH + n) * 2 + 0];
        const double Cim  = (double)C[(h * NH + n) * 2 + 1];
        s_cre[n] = (float)(2.0 * (Cre * fre - Cim * fim));
        s_cim[n] = (float)(2.0 * (Cre * fim + Cim * fre));

        // step multiplier w = exp(dtA * BLOCK), angle reduced mod 2pi
        double r = dim * (double)BLOCK * (1.0 / TWO_PI);
        r -= floor(r);
        double ss, cc;
        sincos(r * TWO_PI, &ss, &cc);
        const double m = exp(dre * (double)BLOCK);
        s_wre[n] = (float)(m * cc);
        s_wim[n] = (float)(m * ss);
        s_dre[n] = (float)dre;
        s_dim[n] = dim;
    }
    __syncthreads();

    float acc[CHUNK];
#pragma unroll
    for (int j = 0; j < CHUNK; ++j) acc[j] = 0.0f;

    const float ftid = (float)tid;
#pragma unroll 1
    for (int n = 0; n < NH; ++n) {
        const float cr = s_cre[n], ci = s_cim[n];
        const float wr = s_wre[n], wi = s_wim[n];

        // base T = exp(dtA * tid): fp64 angle reduction, fp32 sincos/exp
        const double TWO_PI = 6.283185307179586476925287;
        double r = s_dim[n] * (double)tid * (1.0 / TWO_PI);
        r -= floor(r);
        float s, c;
        __sincosf((float)(r * TWO_PI), &s, &c);
        const float mag = __expf(s_dre[n] * ftid);
        float Tr = mag * c, Ti = mag * s;

#pragma unroll
        for (int j = 0; j < CHUNK; ++j) {
            acc[j] = fmaf(cr, Tr, fmaf(-ci, Ti, acc[j]));
            const float nTr = fmaf(Tr, wr, -Ti * wi);
            const float nTi = fmaf(Tr, wi,  Ti * wr);
            Tr = nTr; Ti = nTi;
        }
    }

    float* orow = out + (size_t)h * LLEN + tid;
#pragma unroll
    for (int j = 0; j < CHUNK; ++j) orow[j * BLOCK] = acc[j];
}

extern "C" void kernel_launch(void* const* d_in, const int* in_sizes, int n_in,
                              void* d_out, int out_size, void* d_ws, size_t ws_size,
                              hipStream_t stream) {
    const float* C          = (const float*)d_in[0];
    const float* log_dt     = (const float*)d_in[1];
    const float* log_A_real = (const float*)d_in[2];
    const float* A_imag     = (const float*)d_in[3];
    float* out = (float*)d_out;

    s4d_kernel<<<HDIM, BLOCK, 0, stream>>>(C, log_dt, log_A_real, A_imag, out);
}

// Round 2
// 84.378 us; speedup vs baseline: 1.0468x; 1.0468x over previous
//
#include <hip/hip_runtime.h>
#include <math.h>

#define HDIM   512
#define NH     32
#define LLEN   8192
#define BLOCK  256
#define LSPLIT 2                      // blocks per h-row
#define LPB    (LLEN / LSPLIT)        // 4096 l-values per block
#define JSTEPS (LPB / (BLOCK * 4))    // 4 strided steps of w^1024 per chain

// Grid (LSPLIT, HDIM). Thread tid owns l = ls*LPB + 4*tid + k + 1024*j,
// k in [0,4) = 4 independent complex recurrence chains (ILP), j in [0,JSTEPS)
// advanced by W = exp(dtA*1024). Base angle reduced mod 2pi in fp64.
__global__ __launch_bounds__(BLOCK) void s4d_kernel(
    const float* __restrict__ C,          // (H, NH, 2)
    const float* __restrict__ log_dt,     // (H,)
    const float* __restrict__ log_A_real, // (H, NH)
    const float* __restrict__ A_imag,     // (H, NH)
    float* __restrict__ out)              // (H, LLEN)
{
    __shared__ float  s_cre[NH], s_cim[NH];   // 2 * C_scaled
    __shared__ float  s_w1r[NH], s_w1i[NH];   // exp(dtA * 1)
    __shared__ float  s_Wr[NH],  s_Wi[NH];    // exp(dtA * 1024)
    __shared__ float  s_dre[NH];              // Re(dtA)
    __shared__ double s_dim[NH];              // Im(dtA), fp64 for reduction

    const int h   = blockIdx.y;
    const int ls  = blockIdx.x;
    const int tid = threadIdx.x;

    if (tid < NH) {
        const int n = tid;
        const double TWO_PI = 6.283185307179586476925287;
        const double dt  = exp((double)log_dt[h]);
        const double Are = -exp((double)log_A_real[h * NH + n]);
        const double Aim = (double)A_imag[h * NH + n];
        const double dre = Are * dt, dim = Aim * dt;

        // C_scaled = Cc * (exp(dtA) - 1) / A   (fp64)
        double es, ec;
        sincos(dim, &es, &ec);
        const double em  = exp(dre);
        const double nre = em * ec - 1.0, nim = em * es;
        const double den = Are * Are + Aim * Aim;
        const double fre = (nre * Are + nim * Aim) / den;
        const double fim = (nim * Are - nre * Aim) / den;
        const double Cre = (double)C[(h * NH + n) * 2 + 0];
        const double Cim = (double)C[(h * NH + n) * 2 + 1];
        s_cre[n] = (float)(2.0 * (Cre * fre - Cim * fim));
        s_cim[n] = (float)(2.0 * (Cre * fim + Cim * fre));

        // w1 = exp(dtA)
        s_w1r[n] = (float)(em * ec);
        s_w1i[n] = (float)(em * es);

        // W = exp(dtA * 1024), angle reduced mod 2pi in fp64
        double r = dim * 1024.0 * (1.0 / TWO_PI);
        r -= floor(r);
        double ss, cc;
        sincos(r * TWO_PI, &ss, &cc);
        const double m = exp(dre * 1024.0);
        s_Wr[n] = (float)(m * cc);
        s_Wi[n] = (float)(m * ss);

        s_dre[n] = (float)dre;
        s_dim[n] = dim;
    }
    __syncthreads();

    const int lbase = ls * LPB + 4 * tid;
    const float flbase = (float)lbase;

    float acc[JSTEPS][4];
#pragma unroll
    for (int j = 0; j < JSTEPS; ++j)
#pragma unroll
        for (int k = 0; k < 4; ++k) acc[j][k] = 0.0f;

#pragma unroll 1
    for (int n = 0; n < NH; ++n) {
        const float cr = s_cre[n], ci = s_cim[n];
        const float w1r = s_w1r[n], w1i = s_w1i[n];
        const float Wr = s_Wr[n],  Wi = s_Wi[n];

        // base T0 = exp(dtA * lbase): fp64 angle reduction, fp32 sincos/exp
        const double TWO_PI = 6.283185307179586476925287;
        double r = s_dim[n] * (double)lbase * (1.0 / TWO_PI);
        r -= floor(r);
        float s, c;
        __sincosf((float)(r * TWO_PI), &s, &c);
        const float mag = __expf(s_dre[n] * flbase);

        float Tr[4], Ti[4];
        Tr[0] = mag * c;
        Ti[0] = mag * s;
#pragma unroll
        for (int k = 1; k < 4; ++k) {
            Tr[k] = fmaf(Tr[k-1], w1r, -Ti[k-1] * w1i);
            Ti[k] = fmaf(Tr[k-1], w1i,  Ti[k-1] * w1r);
        }

#pragma unroll
        for (int j = 0; j < JSTEPS; ++j) {
#pragma unroll
            for (int k = 0; k < 4; ++k)
                acc[j][k] = fmaf(cr, Tr[k], fmaf(-ci, Ti[k], acc[j][k]));
            if (j < JSTEPS - 1) {
#pragma unroll
                for (int k = 0; k < 4; ++k) {
                    const float nTr = fmaf(Tr[k], Wr, -Ti[k] * Wi);
                    const float nTi = fmaf(Tr[k], Wi,  Ti[k] * Wr);
                    Tr[k] = nTr; Ti[k] = nTi;
                }
            }
        }
    }

    float* orow = out + (size_t)h * LLEN;
#pragma unroll
    for (int j = 0; j < JSTEPS; ++j) {
        float4 v = make_float4(acc[j][0], acc[j][1], acc[j][2], acc[j][3]);
        *(float4*)(orow + lbase + j * (BLOCK * 4)) = v;
    }
}

extern "C" void kernel_launch(void* const* d_in, const int* in_sizes, int n_in,
                              void* d_out, int out_size, void* d_ws, size_t ws_size,
                              hipStream_t stream) {
    const float* C          = (const float*)d_in[0];
    const float* log_dt     = (const float*)d_in[1];
    const float* log_A_real = (const float*)d_in[2];
    const float* A_imag     = (const float*)d_in[3];
    float* out = (float*)d_out;

    dim3 grid(LSPLIT, HDIM);
    s4d_kernel<<<grid, BLOCK, 0, stream>>>(C, log_dt, log_A_real, A_imag, out);
}